// Round 4
// baseline (221.767 us; speedup 1.0000x reference)
//
#include <hip/hip_runtime.h>
#include <math.h>

#define NCLS 80
#define BINS 16
#define BATCH 32
#define MAX_GT 32
#define NA 8400
#define NT 2100
#define NSLOT 64
#define ALPHA_C 0.25f
#define W_CLS 1.0
#define W_IOU 7.5
#define W_DFL 1.5
#define EPS_F 1e-7f

// ---- cls stream geometry (float4 units) ----
#define IMG_Q4 168000u          // 80ch * 8400 anchors / 4 per image
#define CLS_Q4 5376000u         // 32 * IMG_Q4
#define CLS_GRID 2048
#define CLS_STRIDE (CLS_GRID * 256)   // 524288 threads

// ---- positive-anchor kernel ----
#define POS_GRID 1050           // 1050 * 256 = 268800 side-threads
#define NROWS (CLS_GRID + POS_GRID)   // 3098 partial rows (99 KB ws)

// ---------- focal pieces (logits ~N(0,1): exp(-s) fp32-safe) ----------
__device__ __forceinline__ float focal0(float s)       // focal(s, tt=0)
{
    float e  = __expf(-s);
    float t  = 1.f + e;
    float r  = __builtin_amdgcn_rcpf(t);               // sigmoid(s)
    float lg = __logf(t);
    return 0.75f * r * r * (s + lg);                   // 0.75*sig^2*softplus(s)
}

__device__ __forceinline__ float focal_corr(float s)   // focal(s,1) - focal(s,0)
{
    float e  = __expf(-s);
    float t  = 1.f + e;
    float r  = __builtin_amdgcn_rcpf(t);
    float lg = __logf(t);
    return r * r * (0.25f * e * e * lg - 0.75f * (s + lg));
}

// ---------- per-block partial write: [cls, iou, dfl, cnt] -> row ----------
__device__ __forceinline__ void block_write4(float c0, float c1, float c2, float c3,
                                             double* __restrict__ row)
{
    #pragma unroll
    for (int o = 32; o > 0; o >>= 1) {
        c0 += __shfl_down(c0, o);
        c1 += __shfl_down(c1, o);
        c2 += __shfl_down(c2, o);
        c3 += __shfl_down(c3, o);
    }
    __shared__ float s4[4][4];
    const int wave = threadIdx.x >> 6, lane = threadIdx.x & 63;
    if (lane == 0) { s4[wave][0] = c0; s4[wave][1] = c1; s4[wave][2] = c2; s4[wave][3] = c3; }
    __syncthreads();
    if (threadIdx.x == 0) {
        row[0] = (double)(s4[0][0] + s4[1][0] + s4[2][0] + s4[3][0]);
        row[1] = (double)(s4[0][1] + s4[1][1] + s4[2][1] + s4[3][1]);
        row[2] = (double)(s4[0][2] + s4[1][2] + s4[2][2] + s4[3][2]);
        row[3] = (double)(s4[0][3] + s4[1][3] + s4[2][3] + s4[3][3]);
    }
}

// ---------- K1: pure contiguous stream over all cls logits ----------
__device__ __forceinline__ const float4* cls_map(unsigned v,
    const float4* q0, const float4* q1, const float4* q2)
{
    unsigned b  = v / IMG_Q4;
    unsigned r  = v - b * IMG_Q4;
    return (r < 128000u) ? (q0 + (size_t)b * 230400 + 102400 + r)
         : (r < 160000u) ? (q1 + (size_t)b * 57600  + 25600  + (r - 128000u))
                         : (q2 + (size_t)b * 14400  + 6400   + (r - 160000u));
}

__global__ __launch_bounds__(256) void yolo_cls(
    const float* __restrict__ p0, const float* __restrict__ p1, const float* __restrict__ p2,
    double* __restrict__ blk)
{
    const float4* q0 = (const float4*)p0;
    const float4* q1 = (const float4*)p1;
    const float4* q2 = (const float4*)p2;
    const unsigned gtid = blockIdx.x * 256 + threadIdx.x;

    float c = 0.f;
    unsigned vi = gtid;
    // 10 full strides (10*524288 = 5,242,880 <= CLS_Q4), 5-deep independent loads
    #pragma unroll
    for (int rnd = 0; rnd < 2; ++rnd) {
        float4 q[5];
        #pragma unroll
        for (int u = 0; u < 5; ++u)
            q[u] = *cls_map(vi + u * CLS_STRIDE, q0, q1, q2);
        #pragma unroll
        for (int u = 0; u < 5; ++u)
            c += (focal0(q[u].x) + focal0(q[u].y)) + (focal0(q[u].z) + focal0(q[u].w));
        vi += 5 * CLS_STRIDE;
    }
    // tail stride (predicated; only gtid < 133,120 has work)
    if (vi < CLS_Q4) {
        float4 q = *cls_map(vi, q0, q1, q2);
        c += (focal0(q.x) + focal0(q.y)) + (focal0(q.z) + focal0(q.w));
    }
    block_write4(c, 0.f, 0.f, 0.f, blk + (size_t)blockIdx.x * 4);
}

// ---------- K2: DFL + IoU + sparse-cls correction at positive quads only ----------
template<int HW, int SSTR, int WQ>
__device__ __forceinline__ void pos_scale(
    const float* __restrict__ p, int b, int tl, int k, int gbase, int tid,
    const float* __restrict__ gt_bboxes, const int* __restrict__ gt_labels,
    const int* __restrict__ matched,
    float& c_cls, float& c_iou, float& c_dfl, float& c_cnt)
{
    const int off = tl * 4;
    const int4 m4 = *(const int4*)(matched + (size_t)b * NA + gbase + off);
    const int mm[4] = {m4.x, m4.y, m4.z, m4.w};
    const bool any = (mm[0] >= 0) | (mm[1] >= 0) | (mm[2] >= 0) | (mm[3] >= 0);
    if (!any) return;                                  // 81.5% of quads: no loads at all

    const float stride = (float)SSTR;
    const float inv_s  = 1.f / stride;
    const int h  = tl / WQ;
    const int w0 = (tl - h * WQ) * 4;
    const float cy = ((float)h + 0.5f) * stride;
    const float* pc = p + (size_t)(b * 144 + k * BINS) * HW + off;

    // 16 bin-row loads (active lanes only, exec-masked)
    float4 v[BINS];
    #pragma unroll
    for (int i = 0; i < BINS; ++i)
        v[i] = *(const float4*)(pc + (size_t)(i * HW));

    float se[4] = {0.f, 0.f, 0.f, 0.f}, we[4] = {0.f, 0.f, 0.f, 0.f};
    #pragma unroll
    for (int i = 0; i < BINS; ++i) {
        const float wgt = (float)i;
        float e0 = __expf(v[i].x), e1 = __expf(v[i].y);
        float e2 = __expf(v[i].z), e3 = __expf(v[i].w);
        se[0] += e0; we[0] = fmaf(wgt, e0, we[0]);
        se[1] += e1; we[1] = fmaf(wgt, e1, we[1]);
        se[2] += e2; we[2] = fmaf(wgt, e2, we[2]);
        se[3] += e3; we[3] = fmaf(wgt, e3, we[3]);
    }

    float pd[4];
    #pragma unroll
    for (int j = 0; j < 4; ++j) pd[j] = (we[j] / se[j]) * stride;

    // DFL loss at positive anchors of this quad
    #pragma unroll
    for (int j = 0; j < 4; ++j) {
        if (mm[j] >= 0) {
            const float4 tb = *(const float4*)(gt_bboxes + ((size_t)b * MAX_GT + mm[j]) * 4);
            const float cx = ((float)(w0 + j) + 0.5f) * stride;
            float d = (k == 0) ? (cx - tb.x) : (k == 1) ? (cy - tb.y)
                    : (k == 2) ? (tb.z - cx) : (tb.w - cy);
            float tval = fminf(fmaxf(d, 0.f) * inv_s, (float)(BINS - 1) - 1e-6f);
            int   lo = (int)tval;                      // tval >= 0 -> trunc == floor
            float fr = tval - (float)lo;
            float vlo = pc[(size_t)(lo * HW) + j];     // re-gather (L1 hot; avoids dyn reg idx)
            float vhi = pc[(size_t)((lo + 1) * HW) + j];
            float lse = __logf(se[j]);
            c_dfl += -((1.f - fr) * (vlo - lse) + fr * (vhi - lse));
        }
    }

    // exchange sides within the quad (4 adjacent lanes share `any`)
    const int lbase = (tid & 63) & ~3;
    float d1[4], d2[4], d3[4];
    #pragma unroll
    for (int j = 0; j < 4; ++j) {
        d1[j] = __shfl(pd[j], lbase + 1);              // top    (k=1)
        d2[j] = __shfl(pd[j], lbase + 2);              // right  (k=2)
        d3[j] = __shfl(pd[j], lbase + 3);              // bottom (k=3)
    }
    if (k == 0) {
        #pragma unroll
        for (int j = 0; j < 4; ++j) {
            if (mm[j] >= 0) {
                const float cx = ((float)(w0 + j) + 0.5f) * stride;
                float px1 = cx - pd[j], py1 = cy - d1[j];
                float px2 = cx + d2[j], py2 = cy + d3[j];
                const float4 tb = *(const float4*)(gt_bboxes + ((size_t)b * MAX_GT + mm[j]) * 4);
                float ix1 = fmaxf(px1, tb.x), iy1 = fmaxf(py1, tb.y);
                float ix2 = fminf(px2, tb.z), iy2 = fminf(py2, tb.w);
                float inter  = fmaxf(ix2 - ix1, 0.f) * fmaxf(iy2 - iy1, 0.f);
                float area_p = fmaxf(px2 - px1, 0.f) * fmaxf(py2 - py1, 0.f);
                float area_t = fmaxf(tb.z - tb.x, 0.f) * fmaxf(tb.w - tb.y, 0.f);
                float iou = inter / (area_p + area_t - inter + EPS_F);
                c_iou += 1.f - iou;
                c_cnt += 1.f;
                int lbl = gt_labels[b * MAX_GT + mm[j]];
                float sv = *(p + (size_t)(b * 144 + 4 * BINS + lbl) * HW + off + j);
                c_cls += focal_corr(sv);
            }
        }
    }
}

__global__ __launch_bounds__(256) void yolo_pos(
    const float* __restrict__ p0, const float* __restrict__ p1, const float* __restrict__ p2,
    const float* __restrict__ gt_bboxes, const int* __restrict__ gt_labels,
    const int* __restrict__ matched, double* __restrict__ blk)
{
    const int tid = (int)threadIdx.x;
    const int gdt = (int)blockIdx.x * 256 + tid;       // 0..268799
    const int k   = gdt & 3;
    const int qg  = gdt >> 2;                          // 0..67199
    const int b   = qg / NT;
    const int t   = qg - b * NT;

    float c_cls = 0.f, c_iou = 0.f, c_dfl = 0.f, c_cnt = 0.f;
    if (t < 1600)
        pos_scale<6400,  8, 20>(p0, b, t,        k, 0,    tid,
                                gt_bboxes, gt_labels, matched, c_cls, c_iou, c_dfl, c_cnt);
    else if (t < 2000)
        pos_scale<1600, 16, 10>(p1, b, t - 1600, k, 6400, tid,
                                gt_bboxes, gt_labels, matched, c_cls, c_iou, c_dfl, c_cnt);
    else
        pos_scale< 400, 32,  5>(p2, b, t - 2000, k, 8000, tid,
                                gt_bboxes, gt_labels, matched, c_cls, c_iou, c_dfl, c_cnt);

    block_write4(c_cls, c_iou, c_dfl, c_cnt, blk + (size_t)(CLS_GRID + blockIdx.x) * 4);
}

// ---------- finalize over NROWS per-block partial rows ----------
__global__ __launch_bounds__(1024) void yolo_finalize_blocks(
    const double* __restrict__ blk, float* __restrict__ out)
{
    const int tid = (int)threadIdx.x;
    double s0 = 0.0, s1 = 0.0, s2 = 0.0, s3 = 0.0;
    for (int r = tid; r < NROWS; r += 1024) {
        const double2* rp = (const double2*)(blk + (size_t)r * 4);
        double2 a = rp[0], b = rp[1];
        s0 += a.x; s1 += a.y; s2 += b.x; s3 += b.y;
    }
    #pragma unroll
    for (int o = 32; o > 0; o >>= 1) {
        s0 += __shfl_down(s0, o); s1 += __shfl_down(s1, o);
        s2 += __shfl_down(s2, o); s3 += __shfl_down(s3, o);
    }
    __shared__ double sh[16][4];
    const int wave = tid >> 6, lane = tid & 63;
    if (lane == 0) { sh[wave][0] = s0; sh[wave][1] = s1; sh[wave][2] = s2; sh[wave][3] = s3; }
    __syncthreads();
    if (tid == 0) {
        double c = 0, i = 0, d = 0, n = 0;
        for (int w = 0; w < 16; ++w) { c += sh[w][0]; i += sh[w][1]; d += sh[w][2]; n += sh[w][3]; }
        double np = (n < 1.0) ? 1.0 : n;
        out[0] = (float)(W_CLS * c / np + W_IOU * i / np + W_DFL * d / (np * 4.0));
    }
}

// ---------------- fallback: known-good fused kernel (atomic path) ----------------
__device__ __forceinline__ void block_reduce_atomic(float val, double* __restrict__ target)
{
    __shared__ float s[4];
    __syncthreads();
    #pragma unroll
    for (int o = 32; o > 0; o >>= 1) val += __shfl_down(val, o);
    const int wave = threadIdx.x >> 6, lane = threadIdx.x & 63;
    if (lane == 0) s[wave] = val;
    __syncthreads();
    if (threadIdx.x == 0) atomicAdd(target, (double)(s[0] + s[1] + s[2] + s[3]));
}

__device__ __forceinline__ float focal_elem(float s, float tt)
{
    float e   = __expf(-fabsf(s));
    float inv = 1.f / (1.f + e);
    float prob = (s >= 0.f) ? inv : e * inv;
    float ce  = fmaxf(s, 0.f) - s * tt + __logf(1.f + e);
    float p_t = prob * tt + (1.f - prob) * (1.f - tt);
    float alpha_t = tt * ALPHA_C + (1.f - tt) * (1.f - ALPHA_C);
    float om = 1.f - p_t;
    return alpha_t * om * om * ce;
}

__global__ __launch_bounds__(256) void yolo_loss_fused(
    const float* __restrict__ p0, const float* __restrict__ p1, const float* __restrict__ p2,
    const float* __restrict__ gt_bboxes, const int* __restrict__ gt_labels,
    const int* __restrict__ matched, double* __restrict__ acc)
{
    const int a = blockIdx.x * blockDim.x + threadIdx.x;
    const int b = blockIdx.y;
    const int slot = blockIdx.x & (NSLOT - 1);
    float cls_acc = 0.f, iou_acc = 0.f, dfl_acc = 0.f, pos_cnt = 0.f;
    if (a < NA) {
        const float* p; int HW, W; float stride; int off;
        if (a < 6400)      { p = p0; HW = 6400; W = 80; stride = 8.f;  off = a; }
        else if (a < 8000) { p = p1; HW = 1600; W = 40; stride = 16.f; off = a - 6400; }
        else               { p = p2; HW = 400;  W = 20; stride = 32.f; off = a - 8000; }
        const int h = off / W, w = off - h * W;
        const float cx = ((float)w + 0.5f) * stride, cy = ((float)h + 0.5f) * stride;
        const float* pb = p + ((size_t)b * 144) * (size_t)HW + (size_t)off;
        const int m = matched[(size_t)b * NA + a];
        const bool pos = (m >= 0);
        const int idx = pos ? m : 0;
        const int lbl = gt_labels[b * MAX_GT + idx];
        const float* tbp = gt_bboxes + ((size_t)b * MAX_GT + idx) * 4;
        const float tx1 = tbp[0], ty1 = tbp[1], tx2 = tbp[2], ty2 = tbp[3];
        float tdist[4] = {fmaxf(cx - tx1, 0.f) / stride, fmaxf(cy - ty1, 0.f) / stride,
                          fmaxf(tx2 - cx, 0.f) / stride, fmaxf(ty2 - cy, 0.f) / stride};
        float pdv[4]; float dfl_sum = 0.f;
        #pragma unroll
        for (int k = 0; k < 4; ++k) {
            float tv = fminf(tdist[k], (float)(BINS - 1) - 1e-6f);
            int lo = (int)floorf(tv);
            float fr = tv - (float)lo;
            const float* pcx = pb + (size_t)(k * BINS) * HW;
            float v[BINS];
            #pragma unroll
            for (int i = 0; i < BINS; ++i) v[i] = pcx[(size_t)i * HW];
            float mx = v[0];
            #pragma unroll
            for (int i = 1; i < BINS; ++i) mx = fmaxf(mx, v[i]);
            float se = 0.f, we = 0.f, vlo = 0.f, vhi = 0.f;
            #pragma unroll
            for (int i = 0; i < BINS; ++i) {
                float e = __expf(v[i] - mx);
                se += e; we += (float)i * e;
                vlo = (i == lo) ? v[i] : vlo;
                vhi = (i == lo + 1) ? v[i] : vhi;
            }
            pdv[k] = (we / se) * stride;
            if (pos) { float lse = mx + __logf(se); dfl_sum += -((1.f - fr) * (vlo - lse) + fr * (vhi - lse)); }
        }
        const float* pcls = pb + (size_t)(4 * BINS) * HW;
        #pragma unroll 4
        for (int c = 0; c < NCLS; ++c)
            cls_acc += focal_elem(pcls[(size_t)c * HW], (pos && c == lbl) ? 1.f : 0.f);
        if (pos) {
            float px1 = cx - pdv[0], py1 = cy - pdv[1], px2 = cx + pdv[2], py2 = cy + pdv[3];
            float ix1 = fmaxf(px1, tx1), iy1 = fmaxf(py1, ty1);
            float ix2 = fminf(px2, tx2), iy2 = fminf(py2, ty2);
            float inter  = fmaxf(ix2 - ix1, 0.f) * fmaxf(iy2 - iy1, 0.f);
            float area_p = fmaxf(px2 - px1, 0.f) * fmaxf(py2 - py1, 0.f);
            float area_t = fmaxf(tx2 - tx1, 0.f) * fmaxf(ty2 - ty1, 0.f);
            float iou = inter / (area_p + area_t - inter + EPS_F);
            iou_acc = 1.f - iou; dfl_acc = dfl_sum; pos_cnt = 1.f;
        }
    }
    block_reduce_atomic(cls_acc, &acc[0 * NSLOT + slot]);
    block_reduce_atomic(iou_acc, &acc[1 * NSLOT + slot]);
    block_reduce_atomic(dfl_acc, &acc[2 * NSLOT + slot]);
    block_reduce_atomic(pos_cnt, &acc[3 * NSLOT + slot]);
}

__global__ void yolo_loss_finalize(const double* __restrict__ acc, float* __restrict__ out)
{
    double s[4] = {0.0, 0.0, 0.0, 0.0};
    for (int q = 0; q < 4; ++q)
        for (int i = 0; i < NSLOT; ++i) s[q] += acc[q * NSLOT + i];
    double np = s[3] < 1.0 ? 1.0 : s[3];
    double total = W_CLS * s[0] / np + W_IOU * s[1] / np + W_DFL * s[2] / (np * 4.0);
    out[0] = (float)total;
}

extern "C" void kernel_launch(void* const* d_in, const int* in_sizes, int n_in,
                              void* d_out, int out_size, void* d_ws, size_t ws_size,
                              hipStream_t stream)
{
    const float* p0        = (const float*)d_in[0];
    const float* p1        = (const float*)d_in[1];
    const float* p2        = (const float*)d_in[2];
    const float* gt_bboxes = (const float*)d_in[3];
    const int*   gt_labels = (const int*)d_in[4];
    const int*   matched   = (const int*)d_in[5];
    float*  out = (float*)d_out;

    const size_t need = (size_t)NROWS * 4 * sizeof(double);             // 99,136 B

    if (ws_size >= need) {
        double* blk = (double*)d_ws;
        yolo_cls<<<CLS_GRID, 256, 0, stream>>>(p0, p1, p2, blk);
        yolo_pos<<<POS_GRID, 256, 0, stream>>>(p0, p1, p2, gt_bboxes, gt_labels, matched, blk);
        yolo_finalize_blocks<<<1, 1024, 0, stream>>>(blk, out);
    } else {
        double* acc = (double*)d_ws;
        (void)hipMemsetAsync(acc, 0, 4 * NSLOT * sizeof(double), stream);
        dim3 g((NA + 255) / 256, BATCH);
        yolo_loss_fused<<<g, 256, 0, stream>>>(p0, p1, p2, gt_bboxes, gt_labels, matched, acc);
        yolo_loss_finalize<<<1, 1, 0, stream>>>(acc, out);
    }
}

// Round 6
// 210.114 us; speedup vs baseline: 1.0555x; 1.0555x over previous
//
#include <hip/hip_runtime.h>
#include <math.h>

#define NCLS 80
#define BINS 16
#define BATCH 32
#define MAX_GT 32
#define NA 8400
#define NT 2100
#define NSLOT 64
#define ALPHA_C 0.25f
#define W_CLS 1.0
#define W_IOU 7.5
#define W_DFL 1.5
#define EPS_F 1e-7f

// native vector type for nontemporal builtins (HIP float4 is a class type)
typedef float nf4 __attribute__((ext_vector_type(4)));

// ---- main-kernel geometry: grid dim3(XDIM, BATCH), 256 threads ----
#define X_P0 50                 // p0-cls blocks/image: 50 x 256thr x 10 f4 = 128000 f4
#define X_P1 25                 // p1-cls blocks/image: 25 x 256thr x 5 f4  = 32000 f4
#define X_POS 33                // pos+p2cls blocks/image: 8448 threads (2112 quads + 8000 f4 p2cls)
#define XDIM (X_P0 + X_P1 + X_POS)    // 108
#define NROWS (XDIM * BATCH)          // 3456 partial rows (110,592 B ws)

// ---------- focal pieces (logits ~N(0,1): exp(-s) fp32-safe) ----------
__device__ __forceinline__ float focal0(float s)       // focal(s, tt=0)
{
    float e  = __expf(-s);
    float t  = 1.f + e;
    float r  = __builtin_amdgcn_rcpf(t);               // sigmoid(s)
    float lg = __logf(t);
    return 0.75f * r * r * (s + lg);                   // 0.75*sig^2*softplus(s)
}

__device__ __forceinline__ float focal_corr(float s)   // focal(s,1) - focal(s,0)
{
    float e  = __expf(-s);
    float t  = 1.f + e;
    float r  = __builtin_amdgcn_rcpf(t);
    float lg = __logf(t);
    return r * r * (0.25f * e * e * lg - 0.75f * (s + lg));
}

// ---------- per-block partial write: [cls, iou, dfl, cnt] -> row ----------
__device__ __forceinline__ void block_write4(float c0, float c1, float c2, float c3,
                                             double* __restrict__ row)
{
    #pragma unroll
    for (int o = 32; o > 0; o >>= 1) {
        c0 += __shfl_down(c0, o);
        c1 += __shfl_down(c1, o);
        c2 += __shfl_down(c2, o);
        c3 += __shfl_down(c3, o);
    }
    __shared__ float s4[4][4];
    const int wave = threadIdx.x >> 6, lane = threadIdx.x & 63;
    if (lane == 0) { s4[wave][0] = c0; s4[wave][1] = c1; s4[wave][2] = c2; s4[wave][3] = c3; }
    __syncthreads();
    if (threadIdx.x == 0) {
        row[0] = (double)(s4[0][0] + s4[1][0] + s4[2][0] + s4[3][0]);
        row[1] = (double)(s4[0][1] + s4[1][1] + s4[2][1] + s4[3][1]);
        row[2] = (double)(s4[0][2] + s4[1][2] + s4[2][2] + s4[3][2]);
        row[3] = (double)(s4[0][3] + s4[1][3] + s4[2][3] + s4[3][3]);
    }
}

// ---------- DFL + IoU + sparse-cls correction at positive quads only ----------
// lane = (quad, side k); a quad's 4 sides are 4 adjacent lanes of one wave.
template<int HW, int SSTR, int WQ>
__device__ __forceinline__ void pos_scale(
    const float* __restrict__ p, int b, int tl, int k, int gbase, int tid,
    const float* __restrict__ gt_bboxes, const int* __restrict__ gt_labels,
    const int* __restrict__ matched,
    float& c_cls, float& c_iou, float& c_dfl, float& c_cnt)
{
    const int off = tl * 4;
    const int4 m4 = *(const int4*)(matched + (size_t)b * NA + gbase + off);
    const int mm[4] = {m4.x, m4.y, m4.z, m4.w};
    const bool any = (mm[0] >= 0) | (mm[1] >= 0) | (mm[2] >= 0) | (mm[3] >= 0);
    if (!any) return;                                  // ~81% of quads: no further loads

    const float stride = (float)SSTR;
    const float inv_s  = 1.f / stride;
    const int h  = tl / WQ;
    const int w0 = (tl - h * WQ) * 4;
    const float cy = ((float)h + 0.5f) * stride;
    const float* pc = p + (size_t)(b * 144 + k * BINS) * HW + off;

    // 16 bin-row loads (active lanes only, exec-masked)
    float4 v[BINS];
    #pragma unroll
    for (int i = 0; i < BINS; ++i)
        v[i] = *(const float4*)(pc + (size_t)(i * HW));

    float se[4] = {0.f, 0.f, 0.f, 0.f}, we[4] = {0.f, 0.f, 0.f, 0.f};
    #pragma unroll
    for (int i = 0; i < BINS; ++i) {
        const float wgt = (float)i;
        float e0 = __expf(v[i].x), e1 = __expf(v[i].y);
        float e2 = __expf(v[i].z), e3 = __expf(v[i].w);
        se[0] += e0; we[0] = fmaf(wgt, e0, we[0]);
        se[1] += e1; we[1] = fmaf(wgt, e1, we[1]);
        se[2] += e2; we[2] = fmaf(wgt, e2, we[2]);
        se[3] += e3; we[3] = fmaf(wgt, e3, we[3]);
    }

    float pd[4];
    #pragma unroll
    for (int j = 0; j < 4; ++j) pd[j] = (we[j] / se[j]) * stride;

    // DFL loss at positive anchors of this quad
    #pragma unroll
    for (int j = 0; j < 4; ++j) {
        if (mm[j] >= 0) {
            const float4 tb = *(const float4*)(gt_bboxes + ((size_t)b * MAX_GT + mm[j]) * 4);
            const float cx = ((float)(w0 + j) + 0.5f) * stride;
            float d = (k == 0) ? (cx - tb.x) : (k == 1) ? (cy - tb.y)
                    : (k == 2) ? (tb.z - cx) : (tb.w - cy);
            float tval = fminf(fmaxf(d, 0.f) * inv_s, (float)(BINS - 1) - 1e-6f);
            int   lo = (int)tval;                      // tval >= 0 -> trunc == floor
            float fr = tval - (float)lo;
            float vlo = pc[(size_t)(lo * HW) + j];     // re-gather (L1 hot; no dyn reg idx)
            float vhi = pc[(size_t)((lo + 1) * HW) + j];
            float lse = __logf(se[j]);
            c_dfl += -((1.f - fr) * (vlo - lse) + fr * (vhi - lse));
        }
    }

    // exchange sides within the quad (4 adjacent lanes share `any`)
    const int lbase = (tid & 63) & ~3;
    float d1[4], d2[4], d3[4];
    #pragma unroll
    for (int j = 0; j < 4; ++j) {
        d1[j] = __shfl(pd[j], lbase + 1);              // top    (k=1)
        d2[j] = __shfl(pd[j], lbase + 2);              // right  (k=2)
        d3[j] = __shfl(pd[j], lbase + 3);              // bottom (k=3)
    }
    if (k == 0) {
        #pragma unroll
        for (int j = 0; j < 4; ++j) {
            if (mm[j] >= 0) {
                const float cx = ((float)(w0 + j) + 0.5f) * stride;
                float px1 = cx - pd[j], py1 = cy - d1[j];
                float px2 = cx + d2[j], py2 = cy + d3[j];
                const float4 tb = *(const float4*)(gt_bboxes + ((size_t)b * MAX_GT + mm[j]) * 4);
                float ix1 = fmaxf(px1, tb.x), iy1 = fmaxf(py1, tb.y);
                float ix2 = fminf(px2, tb.z), iy2 = fminf(py2, tb.w);
                float inter  = fmaxf(ix2 - ix1, 0.f) * fmaxf(iy2 - iy1, 0.f);
                float area_p = fmaxf(px2 - px1, 0.f) * fmaxf(py2 - py1, 0.f);
                float area_t = fmaxf(tb.z - tb.x, 0.f) * fmaxf(tb.w - tb.y, 0.f);
                float iou = inter / (area_p + area_t - inter + EPS_F);
                c_iou += 1.f - iou;
                c_cnt += 1.f;
                int lbl = gt_labels[b * MAX_GT + mm[j]];
                float sv = *(p + (size_t)(b * 144 + 4 * BINS + lbl) * HW + off + j);
                c_cls += focal_corr(sv);
            }
        }
    }
}

// ---------- K1: everything, role-partitioned; grid dim3(XDIM, BATCH) ----------
__global__ __launch_bounds__(256) void yolo_main(
    const float* __restrict__ p0, const float* __restrict__ p1, const float* __restrict__ p2,
    const float* __restrict__ gt_bboxes, const int* __restrict__ gt_labels,
    const int* __restrict__ matched, double* __restrict__ blk)
{
    const int b   = (int)blockIdx.y;
    const int x   = (int)blockIdx.x;
    const int tid = (int)threadIdx.x;
    float c_cls = 0.f, c_iou = 0.f, c_dfl = 0.f, c_cnt = 0.f;

    if (x < X_P0) {
        // ---- p0 cls stream: affine, 10 independent nontemporal float4 loads ----
        const nf4* q = (const nf4*)p0 + (size_t)b * 230400 + 102400
                     + (size_t)x * 2560 + tid;
        nf4 v[10];
        #pragma unroll
        for (int i = 0; i < 10; ++i)
            v[i] = __builtin_nontemporal_load(q + i * 256);
        #pragma unroll
        for (int i = 0; i < 10; ++i)
            c_cls += (focal0(v[i].x) + focal0(v[i].y)) + (focal0(v[i].z) + focal0(v[i].w));
    } else if (x < X_P0 + X_P1) {
        // ---- p1 cls stream: affine, 5-deep ----
        const int xx = x - X_P0;
        const nf4* q = (const nf4*)p1 + (size_t)b * 57600 + 25600
                     + (size_t)xx * 1280 + tid;
        nf4 v[5];
        #pragma unroll
        for (int i = 0; i < 5; ++i)
            v[i] = __builtin_nontemporal_load(q + i * 256);
        #pragma unroll
        for (int i = 0; i < 5; ++i)
            c_cls += (focal0(v[i].x) + focal0(v[i].y)) + (focal0(v[i].z) + focal0(v[i].w));
    } else {
        // ---- pos role + p2 cls absorbed ----
        const int xx  = x - (X_P0 + X_P1);
        const int qid = xx * 256 + tid;                // 0..8447
        if (qid < 8000) {                              // p2 cls: one f4 per thread
            nf4 v = __builtin_nontemporal_load(
                (const nf4*)p2 + (size_t)b * 14400 + 6400 + qid);
            c_cls += (focal0(v.x) + focal0(v.y)) + (focal0(v.z) + focal0(v.w));
        }
        const int t = qid >> 2;                        // quad 0..2111 (quad = 4 adjacent lanes)
        const int k = qid & 3;
        if (t < NT) {
            if (t < 1600)
                pos_scale<6400,  8, 20>(p0, b, t,        k, 0,    tid,
                                        gt_bboxes, gt_labels, matched, c_cls, c_iou, c_dfl, c_cnt);
            else if (t < 2000)
                pos_scale<1600, 16, 10>(p1, b, t - 1600, k, 6400, tid,
                                        gt_bboxes, gt_labels, matched, c_cls, c_iou, c_dfl, c_cnt);
            else
                pos_scale< 400, 32,  5>(p2, b, t - 2000, k, 8000, tid,
                                        gt_bboxes, gt_labels, matched, c_cls, c_iou, c_dfl, c_cnt);
        }
    }
    block_write4(c_cls, c_iou, c_dfl, c_cnt, blk + ((size_t)b * XDIM + x) * 4);
}

// ---------- K2: finalize over NROWS per-block partial rows ----------
__global__ __launch_bounds__(1024) void yolo_finalize_blocks(
    const double* __restrict__ blk, float* __restrict__ out)
{
    const int tid = (int)threadIdx.x;
    double s0 = 0.0, s1 = 0.0, s2 = 0.0, s3 = 0.0;
    for (int r = tid; r < NROWS; r += 1024) {
        const double2* rp = (const double2*)(blk + (size_t)r * 4);
        double2 a = rp[0], b = rp[1];
        s0 += a.x; s1 += a.y; s2 += b.x; s3 += b.y;
    }
    #pragma unroll
    for (int o = 32; o > 0; o >>= 1) {
        s0 += __shfl_down(s0, o); s1 += __shfl_down(s1, o);
        s2 += __shfl_down(s2, o); s3 += __shfl_down(s3, o);
    }
    __shared__ double sh[16][4];
    const int wave = tid >> 6, lane = tid & 63;
    if (lane == 0) { sh[wave][0] = s0; sh[wave][1] = s1; sh[wave][2] = s2; sh[wave][3] = s3; }
    __syncthreads();
    if (tid == 0) {
        double c = 0, i = 0, d = 0, n = 0;
        for (int w = 0; w < 16; ++w) { c += sh[w][0]; i += sh[w][1]; d += sh[w][2]; n += sh[w][3]; }
        double np = (n < 1.0) ? 1.0 : n;
        out[0] = (float)(W_CLS * c / np + W_IOU * i / np + W_DFL * d / (np * 4.0));
    }
}

// ---------------- fallback: known-good fused kernel (atomic path) ----------------
__device__ __forceinline__ void block_reduce_atomic(float val, double* __restrict__ target)
{
    __shared__ float s[4];
    __syncthreads();
    #pragma unroll
    for (int o = 32; o > 0; o >>= 1) val += __shfl_down(val, o);
    const int wave = threadIdx.x >> 6, lane = threadIdx.x & 63;
    if (lane == 0) s[wave] = val;
    __syncthreads();
    if (threadIdx.x == 0) atomicAdd(target, (double)(s[0] + s[1] + s[2] + s[3]));
}

__device__ __forceinline__ float focal_elem(float s, float tt)
{
    float e   = __expf(-fabsf(s));
    float inv = 1.f / (1.f + e);
    float prob = (s >= 0.f) ? inv : e * inv;
    float ce  = fmaxf(s, 0.f) - s * tt + __logf(1.f + e);
    float p_t = prob * tt + (1.f - prob) * (1.f - tt);
    float alpha_t = tt * ALPHA_C + (1.f - tt) * (1.f - ALPHA_C);
    float om = 1.f - p_t;
    return alpha_t * om * om * ce;
}

__global__ __launch_bounds__(256) void yolo_loss_fused(
    const float* __restrict__ p0, const float* __restrict__ p1, const float* __restrict__ p2,
    const float* __restrict__ gt_bboxes, const int* __restrict__ gt_labels,
    const int* __restrict__ matched, double* __restrict__ acc)
{
    const int a = blockIdx.x * blockDim.x + threadIdx.x;
    const int b = blockIdx.y;
    const int slot = blockIdx.x & (NSLOT - 1);
    float cls_acc = 0.f, iou_acc = 0.f, dfl_acc = 0.f, pos_cnt = 0.f;
    if (a < NA) {
        const float* p; int HW, W; float stride; int off;
        if (a < 6400)      { p = p0; HW = 6400; W = 80; stride = 8.f;  off = a; }
        else if (a < 8000) { p = p1; HW = 1600; W = 40; stride = 16.f; off = a - 6400; }
        else               { p = p2; HW = 400;  W = 20; stride = 32.f; off = a - 8000; }
        const int h = off / W, w = off - h * W;
        const float cx = ((float)w + 0.5f) * stride, cy = ((float)h + 0.5f) * stride;
        const float* pb = p + ((size_t)b * 144) * (size_t)HW + (size_t)off;
        const int m = matched[(size_t)b * NA + a];
        const bool pos = (m >= 0);
        const int idx = pos ? m : 0;
        const int lbl = gt_labels[b * MAX_GT + idx];
        const float* tbp = gt_bboxes + ((size_t)b * MAX_GT + idx) * 4;
        const float tx1 = tbp[0], ty1 = tbp[1], tx2 = tbp[2], ty2 = tbp[3];
        float tdist[4] = {fmaxf(cx - tx1, 0.f) / stride, fmaxf(cy - ty1, 0.f) / stride,
                          fmaxf(tx2 - cx, 0.f) / stride, fmaxf(ty2 - cy, 0.f) / stride};
        float pdv[4]; float dfl_sum = 0.f;
        #pragma unroll
        for (int k = 0; k < 4; ++k) {
            float tv = fminf(tdist[k], (float)(BINS - 1) - 1e-6f);
            int lo = (int)floorf(tv);
            float fr = tv - (float)lo;
            const float* pcx = pb + (size_t)(k * BINS) * HW;
            float v[BINS];
            #pragma unroll
            for (int i = 0; i < BINS; ++i) v[i] = pcx[(size_t)i * HW];
            float mx = v[0];
            #pragma unroll
            for (int i = 1; i < BINS; ++i) mx = fmaxf(mx, v[i]);
            float se = 0.f, we = 0.f, vlo = 0.f, vhi = 0.f;
            #pragma unroll
            for (int i = 0; i < BINS; ++i) {
                float e = __expf(v[i] - mx);
                se += e; we += (float)i * e;
                vlo = (i == lo) ? v[i] : vlo;
                vhi = (i == lo + 1) ? v[i] : vhi;
            }
            pdv[k] = (we / se) * stride;
            if (pos) { float lse = mx + __logf(se); dfl_sum += -((1.f - fr) * (vlo - lse) + fr * (vhi - lse)); }
        }
        const float* pcls = pb + (size_t)(4 * BINS) * HW;
        #pragma unroll 4
        for (int c = 0; c < NCLS; ++c)
            cls_acc += focal_elem(pcls[(size_t)c * HW], (pos && c == lbl) ? 1.f : 0.f);
        if (pos) {
            float px1 = cx - pdv[0], py1 = cy - pdv[1], px2 = cx + pdv[2], py2 = cy + pdv[3];
            float ix1 = fmaxf(px1, tx1), iy1 = fmaxf(py1, ty1);
            float ix2 = fminf(px2, tx2), iy2 = fminf(py2, ty2);
            float inter  = fmaxf(ix2 - ix1, 0.f) * fmaxf(iy2 - iy1, 0.f);
            float area_p = fmaxf(px2 - px1, 0.f) * fmaxf(py2 - py1, 0.f);
            float area_t = fmaxf(tx2 - tx1, 0.f) * fmaxf(ty2 - ty1, 0.f);
            float iou = inter / (area_p + area_t - inter + EPS_F);
            iou_acc = 1.f - iou; dfl_acc = dfl_sum; pos_cnt = 1.f;
        }
    }
    block_reduce_atomic(cls_acc, &acc[0 * NSLOT + slot]);
    block_reduce_atomic(iou_acc, &acc[1 * NSLOT + slot]);
    block_reduce_atomic(dfl_acc, &acc[2 * NSLOT + slot]);
    block_reduce_atomic(pos_cnt, &acc[3 * NSLOT + slot]);
}

__global__ void yolo_loss_finalize(const double* __restrict__ acc, float* __restrict__ out)
{
    double s[4] = {0.0, 0.0, 0.0, 0.0};
    for (int q = 0; q < 4; ++q)
        for (int i = 0; i < NSLOT; ++i) s[q] += acc[q * NSLOT + i];
    double np = s[3] < 1.0 ? 1.0 : s[3];
    double total = W_CLS * s[0] / np + W_IOU * s[1] / np + W_DFL * s[2] / (np * 4.0);
    out[0] = (float)total;
}

extern "C" void kernel_launch(void* const* d_in, const int* in_sizes, int n_in,
                              void* d_out, int out_size, void* d_ws, size_t ws_size,
                              hipStream_t stream)
{
    const float* p0        = (const float*)d_in[0];
    const float* p1        = (const float*)d_in[1];
    const float* p2        = (const float*)d_in[2];
    const float* gt_bboxes = (const float*)d_in[3];
    const int*   gt_labels = (const int*)d_in[4];
    const int*   matched   = (const int*)d_in[5];
    float*  out = (float*)d_out;

    const size_t need = (size_t)NROWS * 4 * sizeof(double);             // 110,592 B

    if (ws_size >= need) {
        double* blk = (double*)d_ws;
        dim3 g(XDIM, BATCH);
        yolo_main<<<g, 256, 0, stream>>>(p0, p1, p2, gt_bboxes, gt_labels, matched, blk);
        yolo_finalize_blocks<<<1, 1024, 0, stream>>>(blk, out);
    } else {
        double* acc = (double*)d_ws;
        (void)hipMemsetAsync(acc, 0, 4 * NSLOT * sizeof(double), stream);
        dim3 g((NA + 255) / 256, BATCH);
        yolo_loss_fused<<<g, 256, 0, stream>>>(p0, p1, p2, gt_bboxes, gt_labels, matched, acc);
        yolo_loss_finalize<<<1, 1, 0, stream>>>(acc, out);
    }
}